// Round 12
// baseline (99.221 us; speedup 1.0000x reference)
//
#include <hip/hip_runtime.h>

// LinearAttention on MI355X (gfx950) — R12.
// R12 vs R11: k2 GEMM FLIPPED — x is the A-operand (in registers, wave owns a
// 32-px slice), W is the B-operand (16B/lane loads from L2-resident W16).
// Zero LDS for the GEMM; RMS + q-softmax fully via shfl; q-hat stored direct
// to global. Only the k/v -> PV transpose uses LDS (wt/vt, XOR-swizzled).
// ONE barrier total. Grid (32,16)=512 = exactly 2 blocks/CU, one generation.
// Workspace:
//   W16   fp16[384*256]  @ 0         (pre-scaled by g_norm*16)
//   Wo16  fp16[256*128]  @ 196608
//   qhat  fp16[16][4096][128] @ 262144
//   ctx   f32 [16][4096] @ 17039360
//   sume  f32 [16][128]  @ 17301504
//   M     fp16[16][256][128] @ 17309696
//   ctxp  f32 [16][32][4][32][32] @ 18358272   (8.4 MB)
//   sumep f32 [16][128][32] @ 35135488  (ends 35397632)

typedef _Float16 half8 __attribute__((ext_vector_type(8)));
typedef _Float16 half4 __attribute__((ext_vector_type(4)));
typedef float f32x4 __attribute__((ext_vector_type(4)));

#define SCALE_F 0.17677669529663687f

// ---------------- kW: convert weights. W16 = W_qkv * g_norm*16 (per col). ---
__global__ __launch_bounds__(256) void kW(const float* __restrict__ W_qkv,
                                          const float* __restrict__ W_out,
                                          const float* __restrict__ g_norm,
                                          _Float16* __restrict__ W16,
                                          _Float16* __restrict__ Wo16) {
  const int t = threadIdx.x;
  __shared__ float g16s[256];
  g16s[t] = g_norm[t] * 16.0f;
  __syncthreads();
  #pragma unroll
  for (int i = 0; i < 8; ++i) {
    int idx = blockIdx.x * 2048 + i * 256 + t;   // 32768 f32x4 chunks total
    if (idx < 24576) {
      f32x4 v = *(const f32x4*)(W_qkv + (size_t)idx * 4);
      int c0 = (idx & 63) * 4;
      half4 h = {(_Float16)(v[0] * g16s[c0]), (_Float16)(v[1] * g16s[c0 + 1]),
                 (_Float16)(v[2] * g16s[c0 + 2]), (_Float16)(v[3] * g16s[c0 + 3])};
      *(half4*)(W16 + (size_t)idx * 4) = h;
    } else {
      f32x4 v = *(const f32x4*)(W_out + (size_t)(idx - 24576) * 4);
      half4 h = {(_Float16)v[0], (_Float16)v[1], (_Float16)v[2], (_Float16)v[3]};
      *(half4*)(Wo16 + (size_t)(idx - 24576) * 4) = h;
    }
  }
}

// ---------------- k2_mega (R12): flipped GEMM, 1 barrier ----------
// 256 thr, wave w owns px slices {2w, 2w+1} (16 px each). px-tile 128.
__global__ __launch_bounds__(256, 2) void k2_mega(const _Float16* __restrict__ W16,
                                                  const float* __restrict__ x,
                                                  _Float16* __restrict__ qhat,
                                                  float* __restrict__ ctxp,
                                                  float* __restrict__ sumep) {
  const int pt = blockIdx.x, b = blockIdx.y;
  const int p0 = pt * 128;
  const int t = threadIdx.x;
  const int w = t >> 6, l = t & 63;
  const int lg = l >> 4, ll = l & 15;
  const int u = l & 3;
  __shared__ __align__(1024) char smem[67584];
  char* wt = smem;                         // [128 ch][256 B], 16B chunks swz c^(row&15)
  char* vt = smem + 32768;                 // same layout
  float* sums = (float*)(smem + 65536);    // [128][4] per-wave k rowsum partials

  // ---- stage x per slice: f32x4 loads -> quad shfl-transpose -> rms -> af --
  // After transpose lane holds px = slice_base + ll (ll = (l>>2&3)*4 + u).
  half8 af[2][8];
  #pragma unroll
  for (int s = 0; s < 2; ++s) {
    const float* xb = x + ((size_t)b * 256) * 4096 + p0 + (2 * w + s) * 16 + ((l >> 2) & 3) * 4;
    f32x4 tx[16];
    #pragma unroll
    for (int it = 0; it < 16; ++it) {
      int ch = 32 * (it >> 1) + 8 * lg + 4 * (it & 1) + u;
      f32x4 v = *(const f32x4*)(xb + (size_t)ch * 4096);
      // 4x4 transpose within lane quad (uniform-flow shfl, verified R11)
      float sA = __shfl_xor((u & 1) ? v[0] : v[1], 1);
      float sB = __shfl_xor((u & 1) ? v[2] : v[3], 1);
      float a0 = (u & 1) ? sA : v[0];
      float a1 = (u & 1) ? v[1] : sA;
      float a2 = (u & 1) ? sB : v[2];
      float a3 = (u & 1) ? v[3] : sB;
      float sC = __shfl_xor((u & 2) ? a0 : a2, 2);
      float sD = __shfl_xor((u & 2) ? a1 : a3, 2);
      f32x4 o;
      o[0] = (u & 2) ? sC : a0;
      o[1] = (u & 2) ? sD : a1;
      o[2] = (u & 2) ? a2 : sC;
      o[3] = (u & 2) ? a3 : sD;
      tx[it] = o;
    }
    float rs = 0.f;
    #pragma unroll
    for (int it = 0; it < 16; ++it)
      #pragma unroll
      for (int j = 0; j < 4; ++j) rs += tx[it][j] * tx[it][j];
    rs += __shfl_xor(rs, 16);              // reduce over lg groups (full 256 ch)
    rs += __shfl_xor(rs, 32);
    float sinv = rsqrtf(rs + 1e-12f);
    #pragma unroll
    for (int ks = 0; ks < 8; ++ks) {       // af[ks][j]: ch = 32ks + 8lg + j
      half8 hv;
      #pragma unroll
      for (int j = 0; j < 8; ++j)
        hv[j] = (_Float16)(tx[ks * 2 + (j >> 2)][j & 3] * sinv);
      af[s][ks] = hv;
    }
  }

  const f32x4 fz = {0.f, 0.f, 0.f, 0.f};
  _Float16* qb = qhat + ((size_t)b * 4096 + p0) * 128;

  // ---- q: 4 head-pairs of ch_out blocks; softmax over 32 cols via shfl ----
  #pragma unroll
  for (int j = 0; j < 4; ++j) {            // head j
    f32x4 a0[2] = {fz, fz}, a1[2] = {fz, fz};
    #pragma unroll
    for (int ks = 0; ks < 8; ++ks) {
      half8 b0 = *(const half8*)(W16 + (size_t)(j * 32 + ll) * 256 + ks * 32 + lg * 8);
      half8 b1 = *(const half8*)(W16 + (size_t)(j * 32 + 16 + ll) * 256 + ks * 32 + lg * 8);
      #pragma unroll
      for (int s = 0; s < 2; ++s) {
        a0[s] = __builtin_amdgcn_mfma_f32_16x16x32_f16(af[s][ks], b0, a0[s], 0, 0, 0);
        a1[s] = __builtin_amdgcn_mfma_f32_16x16x32_f16(af[s][ks], b1, a1[s], 0, 0, 0);
      }
    }
    // C: row px = slice*16 + lg*4 + rr, col ch = (pair block)*16 + ll
    #pragma unroll
    for (int s = 0; s < 2; ++s) {
      float e0[4], e1[4], inv[4];
      #pragma unroll
      for (int rr = 0; rr < 4; ++rr) {
        e0[rr] = __expf(a0[s][rr]);
        e1[rr] = __expf(a1[s][rr]);
        float v = e0[rr] + e1[rr];
        v += __shfl_xor(v, 1);
        v += __shfl_xor(v, 2);
        v += __shfl_xor(v, 4);
        v += __shfl_xor(v, 8);
        inv[rr] = 1.0f / v;
      }
      #pragma unroll
      for (int rr = 0; rr < 4; ++rr) {
        int px = (2 * w + s) * 16 + lg * 4 + rr;
        qb[(size_t)px * 128 + j * 32 + ll]      = (_Float16)(e0[rr] * inv[rr]);
        qb[(size_t)px * 128 + j * 32 + 16 + ll] = (_Float16)(e1[rr] * inv[rr]);
      }
    }
  }

  // ---- k: exp(logit-10) -> wt scatter + per-wave rowsum partials ----
  #pragma unroll
  for (int m = 0; m < 8; ++m) {
    f32x4 a[2] = {fz, fz};
    #pragma unroll
    for (int ks = 0; ks < 8; ++ks) {
      half8 bw = *(const half8*)(W16 + (size_t)(128 + m * 16 + ll) * 256 + ks * 32 + lg * 8);
      #pragma unroll
      for (int s = 0; s < 2; ++s)
        a[s] = __builtin_amdgcn_mfma_f32_16x16x32_f16(af[s][ks], bw, a[s], 0, 0, 0);
    }
    int row = m * 16 + ll;
    float part = 0.f;
    #pragma unroll
    for (int s = 0; s < 2; ++s) {
      half4 hv;
      #pragma unroll
      for (int rr = 0; rr < 4; ++rr) {
        float e = __expf(a[s][rr] - 10.f);
        part += e;
        hv[rr] = (_Float16)e;
      }
      int c = (2 * w + s) * 2 + (lg >> 1);   // px chunk (8 px / 16B)
      *(half4*)(wt + row * 256 + ((c ^ (row & 15)) << 4) + (lg & 1) * 8) = hv;
    }
    part += __shfl_xor(part, 16);
    part += __shfl_xor(part, 32);
    if (lg == 0) sums[row * 4 + w] = part;
  }

  // ---- v: scatter -> vt ----
  #pragma unroll
  for (int m = 0; m < 8; ++m) {
    f32x4 a[2] = {fz, fz};
    #pragma unroll
    for (int ks = 0; ks < 8; ++ks) {
      half8 bw = *(const half8*)(W16 + (size_t)(256 + m * 16 + ll) * 256 + ks * 32 + lg * 8);
      #pragma unroll
      for (int s = 0; s < 2; ++s)
        a[s] = __builtin_amdgcn_mfma_f32_16x16x32_f16(af[s][ks], bw, a[s], 0, 0, 0);
    }
    int row = m * 16 + ll;
    #pragma unroll
    for (int s = 0; s < 2; ++s) {
      half4 hv;
      #pragma unroll
      for (int rr = 0; rr < 4; ++rr) hv[rr] = (_Float16)a[s][rr];
      int c = (2 * w + s) * 2 + (lg >> 1);
      *(half4*)(vt + row * 256 + ((c ^ (row & 15)) << 4) + (lg & 1) * 8) = hv;
    }
  }

  __syncthreads();                         // the ONLY barrier

  // ---- PV per wave (head = w): ctx[d][e] = sum_px w*v, K = 128 px ----
  {
    f32x4 ca[2][2] = {{fz, fz}, {fz, fz}};
    #pragma unroll
    for (int ks2 = 0; ks2 < 4; ++ks2) {
      half8 a2[2], b2[2];
      #pragma unroll
      for (int ti = 0; ti < 2; ++ti) {
        int row = w * 32 + ti * 16 + ll;
        int c = (ks2 * 4 + lg) ^ (row & 15);
        a2[ti] = *(const half8*)(wt + row * 256 + (c << 4));
        b2[ti] = *(const half8*)(vt + row * 256 + (c << 4));
      }
      #pragma unroll
      for (int ti = 0; ti < 2; ++ti)
        #pragma unroll
        for (int tj = 0; tj < 2; ++tj)
          ca[ti][tj] = __builtin_amdgcn_mfma_f32_16x16x32_f16(a2[ti], b2[tj], ca[ti][tj], 0, 0, 0);
    }
    float* cp = ctxp + (size_t)(((b * 32 + pt) * 4) + w) * 1024;
    #pragma unroll
    for (int ti = 0; ti < 2; ++ti)
      #pragma unroll
      for (int tj = 0; tj < 2; ++tj)
        #pragma unroll
        for (int rr = 0; rr < 4; ++rr)
          cp[(ti * 16 + lg * 4 + rr) * 32 + tj * 16 + ll] = ca[ti][tj][rr];
    if (lg == 0) {
      #pragma unroll
      for (int ti = 0; ti < 2; ++ti) {
        int ch = w * 32 + ti * 16 + ll;
        float s4 = sums[ch * 4] + sums[ch * 4 + 1] + sums[ch * 4 + 2] + sums[ch * 4 + 3];
        sumep[((size_t)b * 128 + ch) * 32 + pt] = s4;
      }
    }
  }
}

// ---------------- k3_reduce: fold ctxp/sumep partials -> ctx, sume ----------
__global__ __launch_bounds__(256) void k3_reduce(const float* __restrict__ ctxp,
                                                 const float* __restrict__ sumep,
                                                 float* __restrict__ ctx,
                                                 float* __restrict__ sume) {
  const int sl = blockIdx.x, b = blockIdx.y;
  const int t = threadIdx.x;
  if (sl == 0 && t < 128) {
    float s = 0.f;
    const float* sp = sumep + ((size_t)b * 128 + t) * 32;
    #pragma unroll 8
    for (int pt = 0; pt < 32; ++pt) s += sp[pt];
    sume[b * 128 + t] = s;
  }
  float a = 0.f;
  const float* p = ctxp + (size_t)b * 32 * 4096 + sl * 256 + t;
  #pragma unroll 8
  for (int pt = 0; pt < 32; ++pt) a += p[(size_t)pt * 4096];
  ctx[(size_t)b * 4096 + sl * 256 + t] = a;
}

// ---------------- k4b: M_h = W_out16[:,h*32..] @ (ctx^T * SCALE/sume), MFMA.
__global__ __launch_bounds__(256) void k4b_fold(const _Float16* __restrict__ Wo16,
                                                const float* __restrict__ ctx,
                                                const float* __restrict__ sumexp,
                                                _Float16* __restrict__ M) {
  const int mq = blockIdx.x, b = blockIdx.y;
  const int t = threadIdx.x;
  const int h = t >> 6, l = t & 63;
  const int m0 = mq * 64;
  const float* cb = ctx + (size_t)(b * 4 + h) * 1024;
  const float* sb = sumexp + b * 128 + h * 32;
  half8 bf[2];
  #pragma unroll
  for (int n0 = 0; n0 < 2; ++n0) {
    int d = n0 * 16 + (l & 15);
    float s = SCALE_F / sb[d];
    const float* ce = cb + d * 32 + (l >> 4) * 8;
    half8 hb;
    #pragma unroll
    for (int j = 0; j < 8; ++j) hb[j] = (_Float16)(ce[j] * s);
    bf[n0] = hb;
  }
  const f32x4 fz = {0.f, 0.f, 0.f, 0.f};
  _Float16* Mb = M + (size_t)(b * 256) * 128;
  #pragma unroll
  for (int mf = 0; mf < 4; ++mf) {
    int row = m0 + mf * 16 + (l & 15);
    half8 af = *(const half8*)(Wo16 + (size_t)row * 128 + h * 32 + (l >> 4) * 8);
    #pragma unroll
    for (int n0 = 0; n0 < 2; ++n0) {
      f32x4 c = __builtin_amdgcn_mfma_f32_16x16x32_f16(af, bf[n0], fz, 0, 0, 0);
      #pragma unroll
      for (int rr = 0; rr < 4; ++rr) {
        int r = m0 + mf * 16 + (l >> 4) * 4 + rr;
        Mb[(size_t)r * 128 + h * 32 + n0 * 16 + (l & 15)] = (_Float16)c[rr];
      }
    }
  }
}

// ---------------- k5: out = rmsnorm(M @ qhat + b_out, g_out), f32 ----------
__global__ __launch_bounds__(256) void k5c_out(const _Float16* __restrict__ M,
                                               const _Float16* __restrict__ qhat,
                                               const float* __restrict__ b_out,
                                               const float* __restrict__ g_out,
                                               float* __restrict__ out) {
  const int pt = blockIdx.x, b = blockIdx.y;
  const int p0 = pt * 64;
  const int t = threadIdx.x;
  const int wid = t >> 6, l = t & 63;
  __shared__ __align__(16) char smem[81920];
  float* rp = (float*)smem;                   // [256][68]
  float* bo = (float*)(smem + 69632);
  float* g16o = (float*)(smem + 70656);
  float* psum = (float*)(smem + 71680);
  float* sinvp = (float*)(smem + 72704);
  const _Float16* Mb = M + (size_t)b * 256 * 128;
  const _Float16* Qb = qhat + ((size_t)b * 4096 + p0) * 128;
  #pragma unroll
  for (int i = 0; i < 16; ++i) {
    int ci = t + 256 * i;
    int r = ci >> 4, c = ci & 15;
    *(half8*)(smem + r * 256 + ((c ^ (r & 15)) << 4)) = *(const half8*)(Mb + (size_t)r * 128 + c * 8);
  }
  #pragma unroll
  for (int i = 0; i < 4; ++i) {
    int ci = t + 256 * i;
    int r = ci >> 4, c = ci & 15;
    *(half8*)(smem + 65536 + r * 256 + ((c ^ (r & 15)) << 4)) = *(const half8*)(Qb + (size_t)r * 128 + c * 8);
  }
  __syncthreads();
  const f32x4 fz = {0.f, 0.f, 0.f, 0.f};
  f32x4 acc[4][4];
  #pragma unroll
  for (int i = 0; i < 4; ++i)
    #pragma unroll
    for (int j = 0; j < 4; ++j) acc[i][j] = fz;
  #pragma unroll
  for (int kk = 0; kk < 4; ++kk) {
    half8 af[4], bf[4];
    int ck = kk * 4 + (l >> 4);
    #pragma unroll
    for (int mf = 0; mf < 4; ++mf) {
      int r = wid * 64 + mf * 16 + (l & 15);
      af[mf] = *(const half8*)(smem + r * 256 + ((ck ^ (r & 15)) << 4));
    }
    #pragma unroll
    for (int nf = 0; nf < 4; ++nf) {
      int r = nf * 16 + (l & 15);
      bf[nf] = *(const half8*)(smem + 65536 + r * 256 + ((ck ^ (r & 15)) << 4));
    }
    #pragma unroll
    for (int mf = 0; mf < 4; ++mf)
      #pragma unroll
      for (int nf = 0; nf < 4; ++nf)
        acc[mf][nf] = __builtin_amdgcn_mfma_f32_16x16x32_f16(af[mf], bf[nf], acc[mf][nf], 0, 0, 0);
  }
  __syncthreads();
  bo[t] = b_out[t];
  g16o[t] = g_out[t] * 16.0f;
  #pragma unroll
  for (int mf = 0; mf < 4; ++mf)
    #pragma unroll
    for (int nf = 0; nf < 4; ++nf)
      #pragma unroll
      for (int rr = 0; rr < 4; ++rr) {
        int r = wid * 64 + mf * 16 + (l >> 4) * 4 + rr;
        int px = nf * 16 + (l & 15);
        rp[r * 68 + px] = acc[mf][nf][rr];
      }
  __syncthreads();
  {
    int px = t & 63, q = t >> 6;
    float s = 0.f;
    #pragma unroll
    for (int i = 0; i < 64; ++i) {
      int r = q * 64 + i;
      float f = rp[r * 68 + px] + bo[r];
      s += f * f;
    }
    psum[px * 4 + q] = s;
  }
  __syncthreads();
  if (t < 64)
    sinvp[t] = rsqrtf(psum[t * 4] + psum[t * 4 + 1] + psum[t * 4 + 2] + psum[t * 4 + 3] + 1e-12f);
  __syncthreads();
  float* ob = out + (size_t)(b * 256) * 4096 + p0;
  #pragma unroll
  for (int i = 0; i < 16; ++i) {
    int idx4 = t + 256 * i;
    int r = idx4 >> 4, px4 = (idx4 & 15) * 4;
    f32x4 v;
    #pragma unroll
    for (int ii = 0; ii < 4; ++ii)
      v[ii] = (rp[r * 68 + px4 + ii] + bo[r]) * sinvp[px4 + ii] * g16o[r];
    *(f32x4*)(ob + (size_t)r * 4096 + px4) = v;
  }
}

extern "C" void kernel_launch(void* const* d_in, const int* in_sizes, int n_in,
                              void* d_out, int out_size, void* d_ws, size_t ws_size,
                              hipStream_t stream) {
  const float* x      = (const float*)d_in[0];
  const float* W_qkv  = (const float*)d_in[1];
  const float* W_out  = (const float*)d_in[2];
  const float* b_out  = (const float*)d_in[3];
  const float* g_norm = (const float*)d_in[4];
  const float* g_out  = (const float*)d_in[5];
  float* out = (float*)d_out;
  char* ws = (char*)d_ws;
  if (ws_size < 35659776) return;

  _Float16* W16   = (_Float16*)(ws);
  _Float16* Wo16  = (_Float16*)(ws + 196608);
  _Float16* qhat  = (_Float16*)(ws + 262144);
  float*    ctx   = (float*)(ws + 17039360);
  float*    sume  = (float*)(ws + 17301504);
  _Float16* M     = (_Float16*)(ws + 17309696);
  float*    ctxp  = (float*)(ws + 18358272);
  float*    sumep = (float*)(ws + 35135488);

  kW<<<16, 256, 0, stream>>>(W_qkv, W_out, g_norm, W16, Wo16);
  k2_mega<<<dim3(32, 16), 256, 0, stream>>>(W16, x, qhat, ctxp, sumep);
  k3_reduce<<<dim3(16, 16), 256, 0, stream>>>(ctxp, sumep, ctx, sume);
  k4b_fold<<<dim3(4, 16), 256, 0, stream>>>(Wo16, ctx, sume, M);
  k5c_out<<<dim3(64, 16), 256, 0, stream>>>(M, qhat, b_out, g_out, out);
}